// Round 22
// baseline (154.339 us; speedup 1.0000x reference)
//
#include <hip/hip_runtime.h>
#include <hip/hip_bf16.h>
#include <float.h>

#define N_NODES 100000
#define HID     512
#define NGRAPH  1024
#define BM      64            // nodes per block
#define NBLK    ((N_NODES + BM - 1) / BM)   // 1563

typedef __bf16 bf16_t;
typedef bf16_t bf16x8 __attribute__((ext_vector_type(8)));
typedef float  f32x4  __attribute__((ext_vector_type(4)));
typedef float  f32x16 __attribute__((ext_vector_type(16)));

// Branch-free gelu: erf via Abramowitz-Stegun 7.1.26 (|err|<=1.5e-7).
__device__ __forceinline__ float fast_gelu(float x) {
    const float z = __builtin_fabsf(x) * 0.70710678118654752f;
    const float t = __fdividef(1.0f, __builtin_fmaf(0.3275911f, z, 1.0f));
    float p = __builtin_fmaf(1.061405429f, t, -1.453152027f);
    p = __builtin_fmaf(p, t, 1.421413741f);
    p = __builtin_fmaf(p, t, -0.284496736f);
    p = __builtin_fmaf(p, t, 0.254829592f);
    p *= t;
    const float e    = __expf(-z * z);
    const float erfz = __builtin_fmaf(-p, e, 1.0f);
    const float s    = __builtin_copysignf(erfz, x);
    return 0.5f * x * (1.0f + s);
}

// ---- Kernel 0: W1 [K][N] f32 -> tiled bf16: unit u=(kt*4+g)*512+col holds
// bf16x8 = W1[kt*32+g*8+e][col], e=0..7 ---------------------------------------
__global__ void __launch_bounds__(256) k_w1t_tiled(const float* __restrict__ w1,
                                                   bf16_t* __restrict__ bt) {
    const int u   = blockIdx.x * 256 + threadIdx.x;   // 0 .. 32767
    const int col = u & 511;
    const int g4  = u >> 9;
    const int k0  = g4 * 8;
    bf16x8 v;
    #pragma unroll
    for (int e = 0; e < 8; ++e)
        v[e] = (bf16_t)w1[(size_t)(k0 + e) * HID + col];
    *reinterpret_cast<bf16x8*>(bt + (size_t)u * 8) = v;
}

// inline-asm W1 load: pins the load (volatile order) and keeps dest live.
#define BLOAD(dst, elemoff)                                                     \
    asm volatile("global_load_dwordx4 %0, %1, off"                              \
                 : "=v"(dst)                                                    \
                 : "v"((const void*)(wbase + (elemoff))))

// ---- Kernel 1: fused GEMM + gelu + dot(W2) -> gate, 32x32x16 MFMA -----------
// Computes z[hidden][node]: A = W1-frag (from bt, asm dist-2 pipeline),
// B = h-frag (LDS). 1024 thr = 16 waves; wave wv owns hidden [wv*32,+32) x
// all 64 nodes (2 col-blocks, acc[2] f32x16 = 32 AGPR). Per K-tile: 4 MFMA +
// 4 ds_read + 2 BLOAD (~10 issue slots vs R19's ~31) -- attacks the
// instruction-issue bound isolated over R9..R21. Epilogue: in-lane hidden dot
// + ONE shfl_xor(32) per col-block (2 shfl vs 48). Counted vmcnt(4/2/0),
// sched_barrier fence (rule #18), stagger sh=wv.
// Layouts: A row=lane&31, k=8*(lane>>5)+e; C/D col=lane&31 (node),
// row=(reg&3)+8*(reg>>2)+4*(lane>>5) (hidden) [guide m74/m101].
__global__ void __launch_bounds__(1024, 4) k_gemm_gate(const float* __restrict__ h,
                                                       const bf16_t* __restrict__ bt,
                                                       const float* __restrict__ b1,
                                                       const float* __restrict__ w2,
                                                       const float* __restrict__ b2,
                                                       float* __restrict__ gate) {
    __shared__ __align__(16) bf16_t As[BM * HID];   // 64KB: [64 nodes][512 k], swizzled
    __shared__ float gp[16][BM];                    // per-wave node partials (4KB)

    const int tid  = threadIdx.x;
    const int lane = tid & 63;
    const int wv   = tid >> 6;     // 0..15 : wave owns hidden [wv*32, wv*32+32)
    const int l31  = lane & 31;
    const int l5   = lane >> 5;    // 0..1

    const int brow = blockIdx.x * BM;

    // ================= stage h: 64 rows x 2KB, coalesced, 4 iters ==============
    #pragma unroll
    for (int i = 0; i < 4; ++i) {
        const int idx = i * 1024 + tid;
        const int row = idx >> 6;
        const int cu  = idx & 63;
        const int grow = brow + row;
        f32x4 s0 = f32x4{0.f, 0.f, 0.f, 0.f}, s1 = s0;
        if (grow < N_NODES) {
            const f32x4* p = reinterpret_cast<const f32x4*>(
                h + (size_t)grow * HID + cu * 8);
            s0 = p[0];
            s1 = p[1];
        }
        bf16x8 v;
        #pragma unroll
        for (int j = 0; j < 4; ++j) { v[j] = (bf16_t)s0[j]; v[4 + j] = (bf16_t)s1[j]; }
        *reinterpret_cast<bf16x8*>(
            (char*)As + row * 1024 + ((cu ^ (row & 7)) * 16)) = v;
    }
    __syncthreads();   // drains staging loads -> vmcnt = 0 entering the K-loop

    // ================= K loop: 16 tiles, 32x32x16, asm dist-2 W1 pipeline ======
    // W1 unit for (kt, ks): wbase + kt*16384 + ks*8192 (bf16 elements)
    const bf16_t* wbase = bt + (size_t)l5 * 4096 + ((size_t)wv * 32 + l31) * 8;
    const char*   a0 = (const char*)As + l31 * 1024;          // cb=0 node row
    const char*   a1 = (const char*)As + (32 + l31) * 1024;   // cb=1 node row
    const int     swz = l31 & 7;                              // (32+l31)&7 == l31&7
    const int     sh  = wv;                                   // per-wave phase
    f32x16 acc[2] = {};

    bf16x8 bcA, bcB;   // W1 for iter t (resident after wait)
    bf16x8 bnA, bnB;   // iter t+1 (in flight)
    bf16x8 bmA, bmB;   // iter t+2 (in flight)
    {   // prologue: issue t=0 and t=1
        const size_t o0 = (size_t)(sh & 15) * 16384;
        BLOAD(bcA, o0); BLOAD(bcB, o0 + 8192);
        const size_t o1 = (size_t)((sh + 1) & 15) * 16384;
        BLOAD(bnA, o1); BLOAD(bnB, o1 + 8192);
    }
    #pragma unroll
    for (int t = 0; t < 16; ++t) {
        const int kt = (t + sh) & 15;
        // issue W1(t+2) -- volatile order keeps this before the wait below
        if (t < 14) {
            const size_t o2 = (size_t)((t + 2 + sh) & 15) * 16384;
            BLOAD(bmA, o2); BLOAD(bmB, o2 + 8192);
        }
        // h fragments from LDS (compiler-managed lgkmcnt)
        const int c0 = (kt * 4 + l5) ^ swz;            // ks=0
        const int c1 = (kt * 4 + 2 + l5) ^ swz;        // ks=1
        bf16x8 h00 = *reinterpret_cast<const bf16x8*>(a0 + c0 * 16);
        bf16x8 h01 = *reinterpret_cast<const bf16x8*>(a0 + c1 * 16);
        bf16x8 h10 = *reinterpret_cast<const bf16x8*>(a1 + c0 * 16);
        bf16x8 h11 = *reinterpret_cast<const bf16x8*>(a1 + c1 * 16);
        // counted wait: iter t's 2 loads are the oldest outstanding
        if (t < 14)       asm volatile("s_waitcnt vmcnt(4)" ::: "memory");
        else if (t == 14) asm volatile("s_waitcnt vmcnt(2)" ::: "memory");
        else              asm volatile("s_waitcnt vmcnt(0)" ::: "memory");
        __builtin_amdgcn_sched_barrier(0);   // rule #18: fence MFMA hoisting
        acc[0] = __builtin_amdgcn_mfma_f32_32x32x16_bf16(bcA, h00, acc[0], 0, 0, 0);
        acc[1] = __builtin_amdgcn_mfma_f32_32x32x16_bf16(bcA, h10, acc[1], 0, 0, 0);
        acc[0] = __builtin_amdgcn_mfma_f32_32x32x16_bf16(bcB, h01, acc[0], 0, 0, 0);
        acc[1] = __builtin_amdgcn_mfma_f32_32x32x16_bf16(bcB, h11, acc[1], 0, 0, 0);
        // rotate pipeline (full unroll -> SSA renames)
        bcA = bnA; bcB = bnB;
        bnA = bmA; bnB = bmB;
    }

    // ================= epilogue: in-lane hidden dot + 1 shfl per col-block =====
    // acc[cb][reg] = z[hidden = wv*32 + (reg&3)+8*(reg>>2)+4*l5][node = cb*32+l31]
    float bArr[4][4], wArr[4][4];
    #pragma unroll
    for (int rg = 0; rg < 4; ++rg) {
        const int hb = wv * 32 + 8 * rg + 4 * l5;
        const float4 bq = *reinterpret_cast<const float4*>(b1 + hb);
        const float4 wq = *reinterpret_cast<const float4*>(w2 + hb);
        bArr[rg][0] = bq.x; bArr[rg][1] = bq.y; bArr[rg][2] = bq.z; bArr[rg][3] = bq.w;
        wArr[rg][0] = wq.x; wArr[rg][1] = wq.y; wArr[rg][2] = wq.z; wArr[rg][3] = wq.w;
    }
    float pr[2] = {0.f, 0.f};
    #pragma unroll
    for (int cb = 0; cb < 2; ++cb) {
        #pragma unroll
        for (int rg = 0; rg < 4; ++rg) {
            #pragma unroll
            for (int j = 0; j < 4; ++j) {
                const float ge = fast_gelu(acc[cb][rg * 4 + j] + bArr[rg][j]);
                pr[cb] = fmaf(ge, wArr[rg][j], pr[cb]);
            }
        }
        pr[cb] += __shfl_xor(pr[cb], 32);   // combine the two 16-hidden halves
    }
    if (lane < 32) {
        gp[wv][l31]      = pr[0];
        gp[wv][32 + l31] = pr[1];
    }
    __syncthreads();
    if (tid < BM) {
        const int grow = brow + tid;
        if (grow < N_NODES) {
            float s = b2[0];
            #pragma unroll
            for (int w = 0; w < 16; ++w) s += gp[w][tid];
            gate[grow] = s;
        }
    }
}

// ---- Kernel 2: segment softmax + weighted pool ------------------------------
__global__ void __launch_bounds__(256) k_pool(const float* __restrict__ h,
                                              const int* __restrict__ bv,
                                              const float* __restrict__ gate,
                                              float* __restrict__ out) {
    const int g   = blockIdx.x;
    const int tid = threadIdx.x;
    __shared__ int   s_bounds[2];
    __shared__ float s_red[4];
    __shared__ float s_alpha[256];

    if (tid == 0) {
        int lo = 0, hi = N_NODES;
        while (lo < hi) { int mid = (lo + hi) >> 1; if (bv[mid] < g) lo = mid + 1; else hi = mid; }
        s_bounds[0] = lo;
        int lo2 = lo, hi2 = N_NODES;
        while (lo2 < hi2) { int mid = (lo2 + hi2) >> 1; if (bv[mid] < g + 1) lo2 = mid + 1; else hi2 = mid; }
        s_bounds[1] = lo2;
    }
    __syncthreads();
    const int start = s_bounds[0], end = s_bounds[1];

    float2 acc = make_float2(0.f, 0.f);
    if (start < end) {
        const int lane = tid & 63, wv = tid >> 6;
        float lm = -FLT_MAX;
        for (int i = start + tid; i < end; i += 256) lm = fmaxf(lm, gate[i]);
        #pragma unroll
        for (int o = 32; o; o >>= 1) lm = fmaxf(lm, __shfl_xor(lm, o));
        if (lane == 0) s_red[wv] = lm;
        __syncthreads();
        const float m = fmaxf(fmaxf(s_red[0], s_red[1]), fmaxf(s_red[2], s_red[3]));
        __syncthreads();
        float ls = 0.f;
        for (int i = start + tid; i < end; i += 256) ls += expf(gate[i] - m);
        #pragma unroll
        for (int o = 32; o; o >>= 1) ls += __shfl_xor(ls, o);
        if (lane == 0) s_red[wv] = ls;
        __syncthreads();
        const float inv = 1.f / (s_red[0] + s_red[1] + s_red[2] + s_red[3]);
        const float* hcol = h + tid * 2;
        for (int base = start; base < end; base += 256) {
            const int j = base + tid;
            const float av = (j < end) ? expf(gate[j] - m) * inv : 0.f;
            __syncthreads();
            s_alpha[tid] = av;
            __syncthreads();
            const int cnt = min(256, end - base);
            for (int jj = 0; jj < cnt; ++jj) {
                const float a = s_alpha[jj];
                const float2 hv = *reinterpret_cast<const float2*>(
                    hcol + (size_t)(base + jj) * HID);
                acc.x = fmaf(a, hv.x, acc.x);
                acc.y = fmaf(a, hv.y, acc.y);
            }
        }
    }
    *reinterpret_cast<float2*>(out + (size_t)g * HID + tid * 2) = acc;
}

// ---- launcher ---------------------------------------------------------------
extern "C" void kernel_launch(void* const* d_in, const int* in_sizes, int n_in,
                              void* d_out, int out_size, void* d_ws, size_t ws_size,
                              hipStream_t stream) {
    const float* h  = (const float*)d_in[0];
    const int*   bv = (const int*)d_in[1];
    const float* W1 = (const float*)d_in[2];
    const float* b1 = (const float*)d_in[3];
    const float* W2 = (const float*)d_in[4];
    const float* b2 = (const float*)d_in[5];
    float* out = (float*)d_out;

    char* ws = (char*)d_ws;
    bf16_t* bt   = (bf16_t*)ws;                    // tiled W1: 524288 B
    float*  gate = (float*)(ws + 524288);          // 400000 B

    k_w1t_tiled<<<dim3(128), dim3(256), 0, stream>>>(W1, bt);
    k_gemm_gate<<<dim3(NBLK), dim3(1024), 0, stream>>>(h, bt, b1, W2, b2, gate);
    k_pool<<<dim3(NGRAPH), dim3(256), 0, stream>>>(h, bv, gate, out);
}

// Round 23
// 137.637 us; speedup vs baseline: 1.1213x; 1.1213x over previous
//
#include <hip/hip_runtime.h>
#include <hip/hip_bf16.h>
#include <float.h>

#define N_NODES 100000
#define HID     512
#define NGRAPH  1024
#define BM      48            // rows per block
#define NBLK    ((N_NODES + BM - 1) / BM)   // 2084

typedef __bf16 bf16_t;
typedef bf16_t bf16x8 __attribute__((ext_vector_type(8)));
typedef float  f32x4  __attribute__((ext_vector_type(4)));

// Branch-free gelu: erf via Abramowitz-Stegun 7.1.26 (|err|<=1.5e-7).
__device__ __forceinline__ float fast_gelu(float x) {
    const float z = __builtin_fabsf(x) * 0.70710678118654752f;
    const float t = __fdividef(1.0f, __builtin_fmaf(0.3275911f, z, 1.0f));
    float p = __builtin_fmaf(1.061405429f, t, -1.453152027f);
    p = __builtin_fmaf(p, t, 1.421413741f);
    p = __builtin_fmaf(p, t, -0.284496736f);
    p = __builtin_fmaf(p, t, 0.254829592f);
    p *= t;
    const float e    = __expf(-z * z);
    const float erfz = __builtin_fmaf(-p, e, 1.0f);
    const float s    = __builtin_copysignf(erfz, x);
    return 0.5f * x * (1.0f + s);
}

// ---- Kernel 0: W1 [K][N] f32 -> tiled bf16 B: unit u=(kt*4+g)*512+col holds
// bf16x8 = W1[kt*32+g*8+e][col], e=0..7 ---------------------------------------
__global__ void __launch_bounds__(256) k_w1t_tiled(const float* __restrict__ w1,
                                                   bf16_t* __restrict__ bt) {
    const int u   = blockIdx.x * 256 + threadIdx.x;   // 0 .. 32767
    const int col = u & 511;
    const int g4  = u >> 9;
    const int k0  = g4 * 8;
    bf16x8 v;
    #pragma unroll
    for (int e = 0; e < 8; ++e)
        v[e] = (bf16_t)w1[(size_t)(k0 + e) * HID + col];
    *reinterpret_cast<bf16x8*>(bt + (size_t)u * 8) = v;
}

// inline-asm B load: pins the load where written (volatile order) and keeps the
// destination live in VGPRs (asm outputs can't be live-range-shrunk) -- the
// compiler collapsed every C-level prefetch (R7: VGPR 68, R15: VGPR 36).
#define BLOAD(dst, elemoff)                                                     \
    asm volatile("global_load_dwordx4 %0, %1, off"                              \
                 : "=v"(dst)                                                    \
                 : "v"((const void*)(bbase + (elemoff))))

// ---- Kernel 1: fused GEMM + gelu + dot(W2) -> gate --------------------------
// Session-best configuration (R19/R21, 137.7us reproduced): BM=48, 8 waves,
// barrier-free staggered K-loop, DISTANCE-2 INLINE-ASM B PIPELINE with counted
// vmcnt (T4): iter t issues B(t+2) via asm, waits vmcnt(8) (B(t) resident,
// 8 newer in flight), sched_barrier(0) fences MFMA hoisting (rule #18).
// Explored and bounded: BM=64/96 (occupancy cliff), 32x32 MFMA (pipe-time,
// not issue-bound), B-in-reg (spill), persistent/dbuf/barriered (all slower).
__global__ void __launch_bounds__(512, 2) k_gemm_gate(const float* __restrict__ h,
                                                      const bf16_t* __restrict__ bt,
                                                      const float* __restrict__ b1,
                                                      const float* __restrict__ w2,
                                                      const float* __restrict__ b2,
                                                      float* __restrict__ gate) {
    __shared__ __align__(16) bf16_t As[BM * HID];   // 48KB: [48 rows][512 k], swizzled
    __shared__ float gp[8][BM];                     // per-wave row partials

    const int tid  = threadIdx.x;
    const int lane = tid & 63;
    const int wv   = tid >> 6;     // 0..7 : wave owns cols [wv*64, wv*64+64)
    const int l15  = lane & 15;
    const int l4   = lane >> 4;    // 0..3

    const int brow = blockIdx.x * BM;

    // ================= stage A: 48 rows x 2KB, coalesced =======================
    #pragma unroll
    for (int i = 0; i < 6; ++i) {
        const int idx = i * 512 + tid;
        const int row = idx >> 6;
        const int cu  = idx & 63;
        const int grow = brow + row;
        f32x4 s0 = f32x4{0.f, 0.f, 0.f, 0.f}, s1 = s0;
        if (grow < N_NODES) {
            const f32x4* p = reinterpret_cast<const f32x4*>(
                h + (size_t)grow * HID + cu * 8);
            s0 = p[0];
            s1 = p[1];
        }
        bf16x8 v;
        #pragma unroll
        for (int j = 0; j < 4; ++j) { v[j] = (bf16_t)s0[j]; v[4 + j] = (bf16_t)s1[j]; }
        *reinterpret_cast<bf16x8*>(
            (char*)As + row * 1024 + ((cu ^ (row & 7)) * 16)) = v;
    }
    __syncthreads();   // drains staging loads -> vmcnt = 0 entering the K-loop

    // ================= K loop: 16 tiles, asm dist-2 B pipeline, staggered ======
    // B unit for (kt, nf): bbase + kt*16384 + nf*128 (bf16 elements)
    const bf16_t* bbase = bt + ((size_t)l4 * 512 + wv * 64 + l15) * 8;
    const char*   abase = (const char*)As + l15 * 1024;
    const int     sh    = (wv << 1) & 15;   // per-wave phase offset
    f32x4 acc[3][4] = {};

    bf16x8 bc0, bc1, bc2, bc3;      // B for iter t (resident after wait)
    bf16x8 bn0, bn1, bn2, bn3;      // B for iter t+1 (in flight)
    bf16x8 bm0, bm1, bm2, bm3;      // B for iter t+2 (in flight)
    {   // prologue: issue t=0 and t=1
        const size_t o0 = (size_t)(sh & 15) * 16384;
        BLOAD(bc0, o0); BLOAD(bc1, o0 + 128); BLOAD(bc2, o0 + 256); BLOAD(bc3, o0 + 384);
        const size_t o1 = (size_t)((1 + sh) & 15) * 16384;
        BLOAD(bn0, o1); BLOAD(bn1, o1 + 128); BLOAD(bn2, o1 + 256); BLOAD(bn3, o1 + 384);
    }
    #pragma unroll
    for (int t = 0; t < 16; ++t) {
        const int kt = (t + sh) & 15;
        // issue B(t+2) -- volatile order keeps this before the wait below
        if (t < 14) {
            const size_t o2 = (size_t)((t + 2 + sh) & 15) * 16384;
            BLOAD(bm0, o2); BLOAD(bm1, o2 + 128); BLOAD(bm2, o2 + 256); BLOAD(bm3, o2 + 384);
        }
        // A fragments (compiler-managed lgkmcnt)
        const int chunkoff = ((kt * 4 + l4) ^ (l15 & 7)) * 16;
        bf16x8 af[3];
        #pragma unroll
        for (int mf = 0; mf < 3; ++mf)
            af[mf] = *reinterpret_cast<const bf16x8*>(abase + mf * 16384 + chunkoff);
        // counted wait: B(t)'s 4 loads are the oldest outstanding
        if (t < 14)       asm volatile("s_waitcnt vmcnt(8)" ::: "memory");
        else if (t == 14) asm volatile("s_waitcnt vmcnt(4)" ::: "memory");
        else              asm volatile("s_waitcnt vmcnt(0)" ::: "memory");
        __builtin_amdgcn_sched_barrier(0);   // rule #18: fence MFMA hoisting
        #pragma unroll
        for (int mf = 0; mf < 3; ++mf) {
            acc[mf][0] = __builtin_amdgcn_mfma_f32_16x16x32_bf16(af[mf], bc0, acc[mf][0], 0, 0, 0);
            acc[mf][1] = __builtin_amdgcn_mfma_f32_16x16x32_bf16(af[mf], bc1, acc[mf][1], 0, 0, 0);
            acc[mf][2] = __builtin_amdgcn_mfma_f32_16x16x32_bf16(af[mf], bc2, acc[mf][2], 0, 0, 0);
            acc[mf][3] = __builtin_amdgcn_mfma_f32_16x16x32_bf16(af[mf], bc3, acc[mf][3], 0, 0, 0);
        }
        // rotate pipeline (full unroll -> SSA renames, no moves)
        bc0 = bn0; bc1 = bn1; bc2 = bn2; bc3 = bn3;
        bn0 = bm0; bn1 = bm1; bn2 = bm2; bn3 = bm3;
    }

    // ================= epilogue: fast_gelu(acc+b1)*w2, reduce 512 cols =========
    float pr[12];
    #pragma unroll
    for (int i = 0; i < 12; ++i) pr[i] = 0.f;
    #pragma unroll
    for (int nf = 0; nf < 4; ++nf) {
        const int cg    = wv * 64 + nf * 16 + l15;
        const float b1v = b1[cg];
        const float w2v = w2[cg];
        #pragma unroll
        for (int mf = 0; mf < 3; ++mf) {
            #pragma unroll
            for (int rr = 0; rr < 4; ++rr) {
                const float ge = fast_gelu(acc[mf][nf][rr] + b1v);
                pr[mf * 4 + rr] = fmaf(ge, w2v, pr[mf * 4 + rr]);
            }
        }
    }
    #pragma unroll
    for (int i = 0; i < 12; ++i) {
        float v = pr[i];
        v += __shfl_xor(v, 1);
        v += __shfl_xor(v, 2);
        v += __shfl_xor(v, 4);
        v += __shfl_xor(v, 8);
        pr[i] = v;
    }
    if (l15 == 0) {
        #pragma unroll
        for (int mf = 0; mf < 3; ++mf)
            #pragma unroll
            for (int rr = 0; rr < 4; ++rr)
                gp[wv][mf * 16 + l4 * 4 + rr] = pr[mf * 4 + rr];
    }
    __syncthreads();
    if (tid < BM) {
        const int grow = brow + tid;
        if (grow < N_NODES) {
            float s = b2[0];
            #pragma unroll
            for (int w = 0; w < 8; ++w) s += gp[w][tid];
            gate[grow] = s;
        }
    }
}

// ---- Kernel 2: segment softmax + weighted pool ------------------------------
__global__ void __launch_bounds__(256) k_pool(const float* __restrict__ h,
                                              const int* __restrict__ bv,
                                              const float* __restrict__ gate,
                                              float* __restrict__ out) {
    const int g   = blockIdx.x;
    const int tid = threadIdx.x;
    __shared__ int   s_bounds[2];
    __shared__ float s_red[4];
    __shared__ float s_alpha[256];

    if (tid == 0) {
        int lo = 0, hi = N_NODES;
        while (lo < hi) { int mid = (lo + hi) >> 1; if (bv[mid] < g) lo = mid + 1; else hi = mid; }
        s_bounds[0] = lo;
        int lo2 = lo, hi2 = N_NODES;
        while (lo2 < hi2) { int mid = (lo2 + hi2) >> 1; if (bv[mid] < g + 1) lo2 = mid + 1; else hi2 = mid; }
        s_bounds[1] = lo2;
    }
    __syncthreads();
    const int start = s_bounds[0], end = s_bounds[1];

    float2 acc = make_float2(0.f, 0.f);
    if (start < end) {
        const int lane = tid & 63, wv = tid >> 6;
        float lm = -FLT_MAX;
        for (int i = start + tid; i < end; i += 256) lm = fmaxf(lm, gate[i]);
        #pragma unroll
        for (int o = 32; o; o >>= 1) lm = fmaxf(lm, __shfl_xor(lm, o));
        if (lane == 0) s_red[wv] = lm;
        __syncthreads();
        const float m = fmaxf(fmaxf(s_red[0], s_red[1]), fmaxf(s_red[2], s_red[3]));
        __syncthreads();
        float ls = 0.f;
        for (int i = start + tid; i < end; i += 256) ls += expf(gate[i] - m);
        #pragma unroll
        for (int o = 32; o; o >>= 1) ls += __shfl_xor(ls, o);
        if (lane == 0) s_red[wv] = ls;
        __syncthreads();
        const float inv = 1.f / (s_red[0] + s_red[1] + s_red[2] + s_red[3]);
        const float* hcol = h + tid * 2;
        for (int base = start; base < end; base += 256) {
            const int j = base + tid;
            const float av = (j < end) ? expf(gate[j] - m) * inv : 0.f;
            __syncthreads();
            s_alpha[tid] = av;
            __syncthreads();
            const int cnt = min(256, end - base);
            for (int jj = 0; jj < cnt; ++jj) {
                const float a = s_alpha[jj];
                const float2 hv = *reinterpret_cast<const float2*>(
                    hcol + (size_t)(base + jj) * HID);
                acc.x = fmaf(a, hv.x, acc.x);
                acc.y = fmaf(a, hv.y, acc.y);
            }
        }
    }
    *reinterpret_cast<float2*>(out + (size_t)g * HID + tid * 2) = acc;
}

// ---- launcher ---------------------------------------------------------------
extern "C" void kernel_launch(void* const* d_in, const int* in_sizes, int n_in,
                              void* d_out, int out_size, void* d_ws, size_t ws_size,
                              hipStream_t stream) {
    const float* h  = (const float*)d_in[0];
    const int*   bv = (const int*)d_in[1];
    const float* W1 = (const float*)d_in[2];
    const float* b1 = (const float*)d_in[3];
    const float* W2 = (const float*)d_in[4];
    const float* b2 = (const float*)d_in[5];
    float* out = (float*)d_out;

    char* ws = (char*)d_ws;
    bf16_t* bt   = (bf16_t*)ws;                    // tiled B: 524288 B
    float*  gate = (float*)(ws + 524288);          // 400000 B

    k_w1t_tiled<<<dim3(128), dim3(256), 0, stream>>>(W1, bt);
    k_gemm_gate<<<dim3(NBLK), dim3(512), 0, stream>>>(h, bt, b1, W2, b2, gate);
    k_pool<<<dim3(NGRAPH), dim3(256), 0, stream>>>(h, bv, gate, out);
}